// Round 4
// baseline (146.825 us; speedup 1.0000x reference)
//
#include <hip/hip_runtime.h>

#define T      64     // num_thetas
#define S      32     // bump_steps
#define CHUNK  64     // nodes per block -> 1024 blocks, 4 blocks/CU
#define NW     4      // waves per block

// Saturation-aware ECT: scaled logit step d = 100*(2.2/31) ~= 7.1, so per
// (node,theta) only s in {s*-1, s*, s*+1} need exact sigmoids (error of
// dropped terms <= 8.2e-4/node << threshold). s >= s*+2 contribute exactly
// 1.0 -> histogram of "ones-start" + inclusive prefix-sum at flush.
// One wave covers all 64 thetas (lane = t) and all 32 s per node.
__global__ __launch_bounds__(256, 4) void ect_kernel(
    const float* __restrict__ x, const float* __restrict__ v,
    const float* __restrict__ lin, const int* __restrict__ batch,
    float* __restrict__ out, int n_points)
{
    __shared__ float acc[T * 33];   // [t][s] exact sigmoids; col 32 = trash for OOB
    __shared__ float hist[T * 33];  // [t][c] ones-start counts; col 32 = "never"
    __shared__ float tot[T * 5];    // [t][wave] partial sums, stride 5 anti-conflict

    const int tid = threadIdx.x;
    const int t   = tid & 63;       // lane == theta
    const int w   = tid >> 6;       // wave id 0..3

    const float lin0     = lin[0];
    const float step     = lin[1] - lin0;                // > 0
    const float inv_step = 1.0f / step;
    const float K2 = (100.0f * step) * 1.4426950408889634f;  // d*log2(e) ~= 10.24
    const float r  = __builtin_amdgcn_exp2f(-K2);            // exp(-d)

    const float v0 = v[0 * T + t];
    const float v1 = v[1 * T + t];
    const float v2 = v[2 * T + t];

    const int base    = blockIdx.x * CHUNK;
    const int rem     = min(CHUNK, n_points - base);
    const int accbase = t * 33;

    int seg_start = 0;
    while (seg_start < rem) {
        for (int i = tid; i < T * 33; i += 256) { acc[i] = 0.0f; hist[i] = 0.0f; }
        __syncthreads();

        // segment end via ballot: lane index == chunk index (CHUNK == 64)
        const int g = batch[base + seg_start];           // wave-uniform broadcast
        const bool bd = (t < rem) && (t > seg_start) && (batch[base + t] != g);
        const unsigned long long mask = __ballot(bd);
        const int seg_end = mask ? (int)__builtin_ctzll(mask) : rem;

        // main loop: wave w takes nodes seg_start+w, +NW, ...
#pragma unroll 2
        for (int n = seg_start + w; n < seg_end; n += NW) {
            const float* xp = x + 3 * (base + n);        // wave-uniform address
            const float nh = xp[0] * v0 + xp[1] * v1 + xp[2] * v2;
            const float f  = (nh - lin0) * inv_step;     // real transition pos
            const float fs = ceilf(f);
            const int   ss = (int)fs;                    // s*: first s with z>=0
            const float gg = fs - f;                     // in [0,1)
            // e = exp(-z) at s = ss-1:  z = d*(gg-1)  ->  e = exp2(K2*(1-gg))
            float e = __builtin_amdgcn_exp2f(K2 * (1.0f - gg));  // in (1, 1211]
#pragma unroll
            for (int j = 0; j < 3; j++) {                // s = ss-1, ss, ss+1
                const int   s   = ss - 1 + j;
                const float sig = __builtin_amdgcn_rcpf(1.0f + e);
                const bool  ok  = ((unsigned)s < 32u);
                const int   col = ok ? s : 32;           // OOB -> trash col
                const float val = ok ? sig : 0.0f;
                atomicAdd(&acc[accbase + col], val);     // ds_add_f32
                e *= r;
            }
            const int c = min(max(ss + 2, 0), 32);       // ones start (32 = never)
            atomicAdd(&hist[accbase + c], 1.0f);
        }
        __syncthreads();

        // flush: ones(s) = sum_{c<=s} hist[t][c]; out[g][s][t] += acc + ones
        float h[8], sumA = 0.0f;
#pragma unroll
        for (int j = 0; j < 8; j++) { h[j] = hist[accbase + 8 * w + j]; sumA += h[j]; }
        tot[t * 5 + w] = sumA;
        __syncthreads();

        float run = 0.0f;
        for (int q = 0; q < w; q++) run += tot[t * 5 + q];   // w wave-uniform
        float* outg = out + (g * S) * T + t;
#pragma unroll
        for (int j = 0; j < 8; j++) {
            run += h[j];                                 // inclusive prefix
            const int   s = 8 * w + j;
            const float valout = acc[accbase + s] + run;
            if (valout != 0.0f) atomicAdd(&outg[s * T], valout);
        }
        __syncthreads();                                 // protect re-zero
        seg_start = seg_end;
    }
}

extern "C" void kernel_launch(void* const* d_in, const int* in_sizes, int n_in,
                              void* d_out, int out_size, void* d_ws, size_t ws_size,
                              hipStream_t stream) {
    const float* x     = (const float*)d_in[0];   // [N,3]
    const float* v     = (const float*)d_in[1];   // [3,64]
    const float* lin   = (const float*)d_in[2];   // [32]
    const int*   batch = (const int*)d_in[3];     // [N], sorted
    float* out = (float*)d_out;                   // [64,32,64]

    const int n_points = in_sizes[0] / 3;
    const int blocks   = (n_points + CHUNK - 1) / CHUNK;

    hipMemsetAsync(d_out, 0, (size_t)out_size * sizeof(float), stream);
    ect_kernel<<<blocks, 256, 0, stream>>>(x, v, lin, batch, out, n_points);
}